// Round 4
// baseline (359.413 us; speedup 1.0000x reference)
//
#include <hip/hip_runtime.h>
#include <hip/hip_bf16.h>

#define NROWS 8192
#define DDIM  256
#define BT    128
#define BK    32
#define NIT   (DDIM / BK)          // 8
#define GT    (NROWS / BT)         // 64
#define NBT   (GT * (GT + 1) / 2)  // 2080 upper-triangle tiles
#define GRID  960                  // 4 blocks/CU * 240 CUs — guaranteed co-resident (LDS 38.1KB, VGPR<=128)

using bf16x8 = __attribute__((ext_vector_type(8))) __bf16;
using f32x4  = __attribute__((ext_vector_type(4))) float;
typedef unsigned long long ull;

__device__ __forceinline__ void glds16(const unsigned short* g, unsigned short* l) {
    // async global->LDS DMA, 16B/lane; LDS dest = wave-uniform base + lane*16
    __builtin_amdgcn_global_load_lds(
        (const __attribute__((address_space(1))) unsigned int*)g,
        (__attribute__((address_space(3))) unsigned int*)l, 16, 0, 0);
}

__device__ __forceinline__ unsigned short f2bf(float f) {
    unsigned int b = __float_as_uint(f);
    unsigned int r = b + 0x7fffu + ((b >> 16) & 1u);
    return (unsigned short)(r >> 16);
}

// Fused: rowstats -> grid spin-barrier -> ticketed triangular GEMM tiles -> last-block finalize.
// dist(i,j) = 1 + a_i*(b_j - 2g) + d_i*(2 m_j);  nv = 0.2 - dist = -0.8 + a_i*nb_j + d_i*nm2_j + (a_i/128)*u
// (u = raw MFMA acc = 256g);  pv = dist - 0.01 = 0.19 - nv.
__global__ __launch_bounds__(256, 4) void snr_fused_kernel(
    const float* __restrict__ x, const int* __restrict__ labels,
    unsigned short* __restrict__ ebf, float* __restrict__ gstats,
    unsigned int* __restrict__ ctrs, float* __restrict__ accums,
    float* __restrict__ out)
{
    __shared__ __align__(16) unsigned short Atile[2][BT * BK];   // 2 x 8 KB
    __shared__ __align__(16) unsigned short Btile[2][BT * BK];   // 2 x 8 KB
    __shared__ __align__(16) float sI[BT * 6];                   // {a,d,A,nb,nm2,lab} per row
    __shared__ __align__(16) float sJ[BT * 6];
    __shared__ float redbuf[4][4];
    __shared__ int curTile;

    const int tid  = threadIdx.x;
    const int lane = tid & 63;
    const int wave = tid >> 6;
    const int bid  = blockIdx.x;

    //================ Phase 1: rowstats (one wave per row) ================
    float regw = 0.f;
    for (int q = bid; q < NROWS / 4; q += GRID) {
        int row = q * 4 + wave;
        const float4 v = reinterpret_cast<const float4*>(x + (size_t)row * DDIM)[lane];
        float ss = v.x * v.x + v.y * v.y + v.z * v.z + v.w * v.w;
        float sm = v.x + v.y + v.z + v.w;
        #pragma unroll
        for (int off = 32; off >= 1; off >>= 1) {
            ss += __shfl_xor(ss, off);
            sm += __shfl_xor(sm, off);
        }
        float invn = 1.0f / sqrtf(ss);
        ushort4 o;
        o.x = f2bf(v.x * invn); o.y = f2bf(v.y * invn);
        o.z = f2bf(v.z * invn); o.w = f2bf(v.w * invn);
        reinterpret_cast<ushort4*>(ebf + (size_t)row * DDIM)[lane] = o;
        if (lane == 0) {
            float Se  = sm * invn;
            float Se2 = ss * invn * invn;
            float m = Se * (1.0f / DDIM);
            float s = Se2 * (1.0f / DDIM);
            float b = s - m * m;
            float a = 1.0f / b;
            float4 g0 = make_float4(a, a * m, a * (1.0f / 128.0f), -b);
            *reinterpret_cast<float4*>(gstats + (size_t)row * 8) = g0;
            float2 g1 = make_float2(-2.0f * m, __int_as_float(labels[row]));
            *reinterpret_cast<float2*>(gstats + (size_t)row * 8 + 4) = g1;
            regw += fabsf(Se);
        }
    }
    if (lane == 0) redbuf[wave][0] = regw;
    __syncthreads();
    if (tid == 0)
        atomicAdd(&accums[4], redbuf[0][0] + redbuf[1][0] + redbuf[2][0] + redbuf[3][0]);

    //================ Grid spin-barrier (all GRID blocks co-resident) ================
    __syncthreads();
    if (tid == 0) {
        __threadfence();
        atomicAdd(&ctrs[0], 1u);
        while (__hip_atomic_load(&ctrs[0], __ATOMIC_RELAXED, __HIP_MEMORY_SCOPE_AGENT) < GRID)
            __builtin_amdgcn_s_sleep(8);
    }
    __syncthreads();
    __threadfence();   // acquire: make all blocks' ebf/gstats visible

    //================ Phase 2: ticketed triangular tiles ================
    const int wr = (wave >> 1) * 64;
    const int wc = (wave & 1) * 64;
    const int mrow = lane & 15;
    const int kch  = lane >> 4;     // 0..3: 16B k-chunk
    const int subr = (lane >> 4) * 4;
    const int cj   = lane & 15;

    // tile-invariant staging descriptors: chunk q in {tid, 256+tid}; row=q>>2; slot=q&3 holds kc=slot^(row&3)
    const int qa0 = tid, qa1 = 256 + tid;
    const int rA0 = qa0 >> 2, rA1 = qa1 >> 2;
    const int cA0 = (qa0 & 3) ^ (rA0 & 3), cA1 = (qa1 & 3) ^ (rA1 & 3);

    // tile-invariant fragment LDS offsets (elems), swizzle-aware
    int offA[4], offB[4];
    #pragma unroll
    for (int t4 = 0; t4 < 4; ++t4) {
        int rA = wr + t4 * 16 + mrow;
        int rB = wc + t4 * 16 + mrow;
        offA[t4] = (rA * 4 + (kch ^ (rA & 3))) * 8;
        offB[t4] = (rB * 4 + (kch ^ (rB & 3))) * 8;
    }

    float ps = 0.f, ns = 0.f;
    unsigned int pcw = 0, ncw = 0;

    while (true) {
        __syncthreads();
        if (tid == 0) curTile = (int)atomicAdd(&ctrs[1], 1u);
        __syncthreads();
        int t = curTile;
        if (t >= NBT) break;

        // decode triangular t -> (bi, bj), bi <= bj
        int bi = (int)((2.0f * GT + 1.0f
                        - sqrtf((2.0f * GT + 1.0f) * (2.0f * GT + 1.0f) - 8.0f * (float)t)) * 0.5f);
        while ((bi + 1) * GT - ((bi + 1) * bi) / 2 <= t) ++bi;
        while (bi * GT - (bi * (bi - 1)) / 2 > t) --bi;
        int bj = bi + (t - (bi * GT - (bi * (bi - 1)) / 2));
        const int rowBase = bi * BT, colBase = bj * BT;
        const bool diag = (bi == bj);

        // stage per-row/per-col epilogue constants into LDS
        {
            int side = (tid < BT) ? rowBase : colBase;
            int r    = tid & (BT - 1);
            float* dst = (tid < BT) ? (sI + r * 6) : (sJ + r * 6);
            const float* src = gstats + (size_t)(side + r) * 8;
            float4 p0 = *reinterpret_cast<const float4*>(src);
            float2 p1 = *reinterpret_cast<const float2*>(src + 4);
            *reinterpret_cast<float2*>(dst + 0) = make_float2(p0.x, p0.y);
            *reinterpret_cast<float2*>(dst + 2) = make_float2(p0.z, p0.w);
            *reinterpret_cast<float2*>(dst + 4) = p1;
        }
        asm volatile("s_waitcnt lgkmcnt(0)" ::: "memory");  // stats ds_writes done before first barrier

        // staging pointers for this tile
        const unsigned short* ga0 = ebf + (size_t)(rowBase + rA0) * DDIM + cA0 * 8;
        const unsigned short* ga1 = ebf + (size_t)(rowBase + rA1) * DDIM + cA1 * 8;
        const unsigned short* gb0 = ebf + (size_t)(colBase + rA0) * DDIM + cA0 * 8;
        const unsigned short* gb1 = ebf + (size_t)(colBase + rA1) * DDIM + cA1 * 8;

        // preload iter 0 -> buffer 0
        glds16(ga0, &Atile[0][qa0 * 8]);
        glds16(ga1, &Atile[0][qa1 * 8]);
        glds16(gb0, &Btile[0][qa0 * 8]);
        glds16(gb1, &Btile[0][qa1 * 8]);

        f32x4 acc[4][4];
        #pragma unroll
        for (int a = 0; a < 4; ++a)
            #pragma unroll
            for (int b = 0; b < 4; ++b)
                acc[a][b] = (f32x4){0.f, 0.f, 0.f, 0.f};

        // pipelined K-loop: next iter's loads stay in flight across both barriers
        #pragma unroll
        for (int it = 0; it < NIT; ++it) {
            if (it + 1 < NIT) {
                int ko = (it + 1) * BK;
                int b  = (it + 1) & 1;
                glds16(ga0 + ko, &Atile[b][qa0 * 8]);
                glds16(ga1 + ko, &Atile[b][qa1 * 8]);
                glds16(gb0 + ko, &Btile[b][qa0 * 8]);
                glds16(gb1 + ko, &Btile[b][qa1 * 8]);
                asm volatile("s_waitcnt vmcnt(4)" ::: "memory");   // oldest 4 (current buf) landed
            } else {
                asm volatile("s_waitcnt vmcnt(0)" ::: "memory");
            }
            asm volatile("s_barrier" ::: "memory");

            const unsigned short* Ab = &Atile[it & 1][0];
            const unsigned short* Bb = &Btile[it & 1][0];
            bf16x8 aF[4], bF[4];
            #pragma unroll
            for (int t4 = 0; t4 < 4; ++t4) {
                aF[t4] = *reinterpret_cast<const bf16x8*>(Ab + offA[t4]);
                bF[t4] = *reinterpret_cast<const bf16x8*>(Bb + offB[t4]);
            }
            #pragma unroll
            for (int ti = 0; ti < 4; ++ti)
                #pragma unroll
                for (int tj = 0; tj < 4; ++tj)
                    acc[ti][tj] = __builtin_amdgcn_mfma_f32_16x16x32_bf16(aF[ti], bF[tj], acc[ti][tj], 0, 0, 0);

            asm volatile("s_barrier" ::: "memory");   // readers done before next overwrite
        }

        // ---- epilogue ----
        float aJ[4], dJ[4], AJ[4], nbJ[4], nmJ[4];
        unsigned LJb[4];
        #pragma unroll
        for (int tj = 0; tj < 4; ++tj) {
            int lj = wc + tj * 16 + cj;
            float2 e0 = *reinterpret_cast<const float2*>(sJ + lj * 6);
            float2 e1 = *reinterpret_cast<const float2*>(sJ + lj * 6 + 2);
            float2 e2 = *reinterpret_cast<const float2*>(sJ + lj * 6 + 4);
            aJ[tj] = e0.x; dJ[tj] = e0.y; AJ[tj] = e1.x; nbJ[tj] = e1.y; nmJ[tj] = e2.x;
            LJb[tj] = __float_as_uint(e2.y);
        }

        if (!diag) {
            #pragma unroll
            for (int ti = 0; ti < 4; ++ti) {
                #pragma unroll
                for (int r = 0; r < 4; ++r) {
                    int li = wr + ti * 16 + subr + r;
                    float2 f0 = *reinterpret_cast<const float2*>(sI + li * 6);
                    float2 f1 = *reinterpret_cast<const float2*>(sI + li * 6 + 2);
                    float2 f2 = *reinterpret_cast<const float2*>(sI + li * 6 + 4);
                    float ai = f0.x, di = f0.y, Ai = f1.x, nbi = f1.y, nmi = f2.x;
                    unsigned Lib = __float_as_uint(f2.y);
                    #pragma unroll
                    for (int tj = 0; tj < 4; ++tj) {
                        float u = acc[ti][tj][r];
                        float Nij = fmaf(ai, nbJ[tj], fmaf(di, nmJ[tj], -0.8f));
                        float nv1 = fmaf(Ai, u, Nij);
                        float Nji = fmaf(aJ[tj], nbi, fmaf(dJ[tj], nmi, -0.8f));
                        float nv2 = fmaf(AJ[tj], u, Nji);
                        ull ms = __ballot(Lib == LJb[tj]);
                        if (ms == 0ull) {
                            // fast path: no same-label pair in the whole wave
                            ns += fmaxf(nv1, 0.f) + fmaxf(nv2, 0.f);
                            ncw += (unsigned)__popcll(__ballot(nv1 > 0.f))
                                 + (unsigned)__popcll(__ballot(nv2 > 0.f));
                        } else {
                            bool same = (Lib == LJb[tj]);
                            float pv1 = 0.19f - nv1, pv2 = 0.19f - nv2;
                            bool n1 = !same && nv1 > 0.f, n2 = !same && nv2 > 0.f;
                            bool p1 = same && pv1 > 0.f,  p2 = same && pv2 > 0.f;
                            ns += (n1 ? nv1 : 0.f) + (n2 ? nv2 : 0.f);
                            ps += (p1 ? pv1 : 0.f) + (p2 ? pv2 : 0.f);
                            ncw += (unsigned)__popcll(__ballot(n1)) + (unsigned)__popcll(__ballot(n2));
                            pcw += (unsigned)__popcll(__ballot(p1)) + (unsigned)__popcll(__ballot(p2));
                        }
                    }
                }
            }
        } else {
            #pragma unroll
            for (int ti = 0; ti < 4; ++ti) {
                #pragma unroll
                for (int r = 0; r < 4; ++r) {
                    int li = wr + ti * 16 + subr + r;
                    float2 f0 = *reinterpret_cast<const float2*>(sI + li * 6);
                    float2 f1 = *reinterpret_cast<const float2*>(sI + li * 6 + 2);
                    float2 f2 = *reinterpret_cast<const float2*>(sI + li * 6 + 4);
                    float ai = f0.x, di = f0.y, Ai = f1.x;
                    unsigned Lib = __float_as_uint(f2.y);
                    #pragma unroll
                    for (int tj = 0; tj < 4; ++tj) {
                        int lj = wc + tj * 16 + cj;
                        float u = acc[ti][tj][r];
                        float Nij = fmaf(ai, nbJ[tj], fmaf(di, nmJ[tj], -0.8f));
                        float nv1 = fmaf(Ai, u, Nij);
                        bool same = (Lib == LJb[tj]);
                        float pv1 = 0.19f - nv1;
                        bool p1 = same && (li != lj) && pv1 > 0.f;   // exclude the exact diagonal
                        bool n1 = !same && nv1 > 0.f;
                        ns += n1 ? nv1 : 0.f;
                        ps += p1 ? pv1 : 0.f;
                        ncw += (unsigned)__popcll(__ballot(n1));
                        pcw += (unsigned)__popcll(__ballot(p1));
                    }
                }
            }
        }
    }

    //================ Tail: block reduce + last-block finalize ================
    #pragma unroll
    for (int off = 32; off >= 1; off >>= 1) {
        ps += __shfl_down(ps, off);
        ns += __shfl_down(ns, off);
    }
    if (lane == 0) {
        redbuf[wave][0] = ps; redbuf[wave][1] = ns;
        redbuf[wave][2] = (float)pcw; redbuf[wave][3] = (float)ncw;
    }
    __syncthreads();
    if (tid == 0) {
        float a0 = 0, a1 = 0, a2 = 0, a3 = 0;
        #pragma unroll
        for (int w = 0; w < 4; ++w) {
            a0 += redbuf[w][0]; a1 += redbuf[w][1];
            a2 += redbuf[w][2]; a3 += redbuf[w][3];
        }
        atomicAdd(&accums[0], a0);
        atomicAdd(&accums[1], a1);
        atomicAdd(&accums[2], a2);
        atomicAdd(&accums[3], a3);
        __threadfence();
        unsigned old = atomicAdd(&ctrs[2], 1u);
        if (old == GRID - 1) {
            __threadfence();
            float A0 = __hip_atomic_load(&accums[0], __ATOMIC_RELAXED, __HIP_MEMORY_SCOPE_AGENT);
            float A1 = __hip_atomic_load(&accums[1], __ATOMIC_RELAXED, __HIP_MEMORY_SCOPE_AGENT);
            float A2 = __hip_atomic_load(&accums[2], __ATOMIC_RELAXED, __HIP_MEMORY_SCOPE_AGENT);
            float A3 = __hip_atomic_load(&accums[3], __ATOMIC_RELAXED, __HIP_MEMORY_SCOPE_AGENT);
            float A4 = __hip_atomic_load(&accums[4], __ATOMIC_RELAXED, __HIP_MEMORY_SCOPE_AGENT);
            float pos = A0 / (A2 + 1e-12f);
            float neg = A1 / (A3 + 1e-12f);
            out[0] = pos + neg + A4 * (0.1f / (float)NROWS);
        }
    }
}

extern "C" void kernel_launch(void* const* d_in, const int* in_sizes, int n_in,
                              void* d_out, int out_size, void* d_ws, size_t ws_size,
                              hipStream_t stream) {
    const float* embeds = (const float*)d_in[0];
    const int*   labels = (const int*)d_in[1];
    float* out = (float*)d_out;

    char* ws = (char*)d_ws;
    unsigned short* ebf = (unsigned short*)ws;                        // 4 MB
    float* gstats = (float*)(ws + (size_t)NROWS * DDIM * 2);          // 8192*8 floats = 256 KB
    unsigned int* ctrs = (unsigned int*)(ws + (size_t)NROWS * DDIM * 2 + NROWS * 8 * sizeof(float));
    float* accums = (float*)((char*)ctrs + 32);                       // [ps, ns, pc, nc, reg]

    hipMemsetAsync(ctrs, 0, 64, stream);   // zero barrier/ticket/done counters + accums

    snr_fused_kernel<<<GRID, 256, 0, stream>>>(embeds, labels, ebf, gstats, ctrs, accums, out);
}

// Round 6
// 289.705 us; speedup vs baseline: 1.2406x; 1.2406x over previous
//
#include <hip/hip_runtime.h>
#include <hip/hip_bf16.h>

#define NROWS 8192
#define DDIM  256
#define KAUG  320                  // 256 data + [a,2d,1] tail + zero pad to BK multiple
#define BT    128
#define BK    64
#define NIT   (KAUG / BK)          // 5
#define GT    (NROWS / BT)         // 64
#define NTILE (GT * GT)            // 4096
#define GRID  768                  // 3 blocks/CU co-resident (VGPR cap 168, LDS 33.3KB <= 53KB)

using bf16x8 = __attribute__((ext_vector_type(8))) __bf16;
using f32x4  = __attribute__((ext_vector_type(4))) float;
typedef unsigned long long ull;

__device__ __forceinline__ void glds16(const unsigned short* g, unsigned short* l) {
    // async global->LDS DMA, 16B/lane; LDS dest = wave-uniform base + lane*16
    __builtin_amdgcn_global_load_lds(
        (const __attribute__((address_space(1))) unsigned int*)g,
        (__attribute__((address_space(3))) unsigned int*)l, 16, 0, 0);
}

__device__ __forceinline__ unsigned short f2bf(float f) {
    unsigned int b = __float_as_uint(f);
    unsigned int r = b + 0x7fffu + ((b >> 16) & 1u);
    return (unsigned short)(r >> 16);
}

// Augmented-GEMM: dist(i,j) = X_i . Y_j with
//   X_i = [(-2a_i/256)*e_i, a_i, 2d_i, 1, 0...],  Y_j = [e_j, b_j, m_j, 1, 0...]
// MFMA accumulator IS dist. dist(i,i) = 0 (+-0.005) < 0.01 -> diagonal self-excludes.
__global__ __launch_bounds__(256, 3) void snr_fused_kernel(
    const float* __restrict__ x, const int* __restrict__ labels,
    unsigned short* __restrict__ X, unsigned short* __restrict__ Y,
    unsigned int* __restrict__ ctrs, float* __restrict__ accums,
    float* __restrict__ out)
{
    __shared__ __align__(16) unsigned short As[BT * BK];   // 16 KB, XOR-swizzled chunks
    __shared__ __align__(16) unsigned short Bs[BT * BK];   // 16 KB
    __shared__ __align__(16) int sLi[BT];
    __shared__ __align__(16) int sLj[BT];
    __shared__ float redbuf[4][4];
    __shared__ int curTile;

    const int tid  = threadIdx.x;
    const int lane = tid & 63;
    const int wave = tid >> 6;
    const int bid  = blockIdx.x;

    //================ Phase 1: rowstats -> build augmented X, Y ================
    float regw = 0.f;
    for (int row = bid * 4 + wave; row < NROWS; row += GRID * 4) {
        const float4 v = reinterpret_cast<const float4*>(x + (size_t)row * DDIM)[lane];
        float ss = v.x * v.x + v.y * v.y + v.z * v.z + v.w * v.w;
        float sm = v.x + v.y + v.z + v.w;
        #pragma unroll
        for (int off = 32; off >= 1; off >>= 1) {
            ss += __shfl_xor(ss, off);
            sm += __shfl_xor(sm, off);
        }
        float invn = 1.0f / sqrtf(ss);
        float Se = sm * invn;
        float m  = Se * (1.0f / DDIM);
        float s  = (ss * invn * invn) * (1.0f / DDIM);
        float b  = s - m * m;
        float a  = 1.0f / b;
        float d  = a * m;

        float cX = (-2.0f * a * (1.0f / 256.0f)) * invn;
        float cY = invn;
        ushort4 xo, yo;
        xo.x = f2bf(v.x * cX); xo.y = f2bf(v.y * cX);
        xo.z = f2bf(v.z * cX); xo.w = f2bf(v.w * cX);
        yo.x = f2bf(v.x * cY); yo.y = f2bf(v.y * cY);
        yo.z = f2bf(v.z * cY); yo.w = f2bf(v.w * cY);
        reinterpret_cast<ushort4*>(X + (size_t)row * KAUG)[lane] = xo;
        reinterpret_cast<ushort4*>(Y + (size_t)row * KAUG)[lane] = yo;
        if (lane < 16) {
            ushort4 tx = {0, 0, 0, 0}, ty = {0, 0, 0, 0};
            if (lane == 0) {
                tx.x = f2bf(a); tx.y = f2bf(2.0f * d); tx.z = f2bf(1.0f);
                ty.x = f2bf(b); ty.y = f2bf(m);        ty.z = f2bf(1.0f);
            }
            reinterpret_cast<ushort4*>(X + (size_t)row * KAUG + 256)[lane] = tx;
            reinterpret_cast<ushort4*>(Y + (size_t)row * KAUG + 256)[lane] = ty;
        }
        if (lane == 0) regw += fabsf(Se);
    }
    if (lane == 0) redbuf[wave][0] = regw;
    __syncthreads();
    if (tid == 0)
        atomicAdd(&accums[4], redbuf[0][0] + redbuf[1][0] + redbuf[2][0] + redbuf[3][0]);

    //================ Grid spin-barrier (all GRID blocks co-resident) ================
    __syncthreads();
    if (tid == 0) {
        __threadfence();
        atomicAdd(&ctrs[0], 1u);
        while (__hip_atomic_load(&ctrs[0], __ATOMIC_RELAXED, __HIP_MEMORY_SCOPE_AGENT) < GRID)
            __builtin_amdgcn_s_sleep(8);
    }
    __syncthreads();
    __threadfence();   // acquire: all blocks' X/Y visible

    //================ Phase 2: ticketed full-grid tiles ================
    const int wr = (wave >> 1) * 64;
    const int wc = (wave & 1) * 64;
    const int mrow = lane & 15;
    const int kch  = lane >> 4;       // 0..3
    const int subr = (lane >> 4) * 4;
    const int cj   = lane & 15;

    // staging: 4 chunks per array per thread: q=p*256+tid; row=q>>3; slot=q&7 holds kc=slot^(row&7)
    int ldRow[4], ldKc[4];
    #pragma unroll
    for (int p = 0; p < 4; ++p) {
        int q = p * 256 + tid;
        ldRow[p] = q >> 3;
        ldKc[p]  = (q & 7) ^ ((q >> 3) & 7);
    }

    // fragment LDS offsets (elems), swizzle-aware (r3-verified: zero conflicts)
    int offA[4][2], offB[4][2];
    #pragma unroll
    for (int t4 = 0; t4 < 4; ++t4) {
        int rA = wr + t4 * 16 + mrow;
        int rB = wc + t4 * 16 + mrow;
        #pragma unroll
        for (int h = 0; h < 2; ++h) {
            offA[t4][h] = (rA * 8 + ((h * 4 + kch) ^ (rA & 7))) * 8;
            offB[t4][h] = (rB * 8 + ((h * 4 + kch) ^ (rB & 7))) * 8;
        }
    }

    float ps = 0.f, ns = 0.f;
    unsigned int pcw = 0, ncw = 0;

    while (true) {
        __syncthreads();                    // prior tile's LDS reads complete
        if (tid == 0) curTile = (int)atomicAdd(&ctrs[1], 1u);
        __syncthreads();
        int t = curTile;
        if (t >= NTILE) break;

        const int rowBase = (t >> 6) * BT;
        const int colBase = (t & 63) * BT;

        // labels to LDS (the K-loop's first __syncthreads covers these writes)
        if (tid < BT) sLi[tid] = labels[rowBase + tid];
        else          sLj[tid - BT] = labels[colBase + tid - BT];

        f32x4 accv[4][4];
        #pragma unroll
        for (int a = 0; a < 4; ++a)
            #pragma unroll
            for (int b = 0; b < 4; ++b)
                accv[a][b] = (f32x4){0.f, 0.f, 0.f, 0.f};

        // K-loop: m97-style — __syncthreads() drains glds (vmcnt) before fragment reads
        #pragma unroll
        for (int it = 0; it < NIT; ++it) {
            const int ko = it * BK;
            #pragma unroll
            for (int p = 0; p < 4; ++p) {
                const unsigned short* gx = X + (size_t)(rowBase + ldRow[p]) * KAUG + ko + ldKc[p] * 8;
                const unsigned short* gy = Y + (size_t)(colBase + ldRow[p]) * KAUG + ko + ldKc[p] * 8;
                glds16(gx, &As[(p * 256 + tid) * 8]);
                glds16(gy, &Bs[(p * 256 + tid) * 8]);
            }
            __syncthreads();

            #pragma unroll
            for (int h = 0; h < 2; ++h) {
                bf16x8 aF[4], bF[4];
                #pragma unroll
                for (int t4 = 0; t4 < 4; ++t4) {
                    aF[t4] = *reinterpret_cast<const bf16x8*>(As + offA[t4][h]);
                    bF[t4] = *reinterpret_cast<const bf16x8*>(Bs + offB[t4][h]);
                }
                #pragma unroll
                for (int ti = 0; ti < 4; ++ti)
                    #pragma unroll
                    for (int tj = 0; tj < 4; ++tj)
                        accv[ti][tj] = __builtin_amdgcn_mfma_f32_16x16x32_bf16(
                            aF[ti], bF[tj], accv[ti][tj], 0, 0, 0);
            }
            __syncthreads();                // reads complete before next iter's DMA overwrite
        }

        // ---- epilogue: accv[ti][tj][r] == dist(i,j) ----
        int Li[16], Lj[4];
        #pragma unroll
        for (int t4 = 0; t4 < 4; ++t4) {
            int4 q4 = *reinterpret_cast<const int4*>(&sLi[wr + t4 * 16 + subr]);
            Li[t4 * 4 + 0] = q4.x; Li[t4 * 4 + 1] = q4.y;
            Li[t4 * 4 + 2] = q4.z; Li[t4 * 4 + 3] = q4.w;
        }
        #pragma unroll
        for (int tj = 0; tj < 4; ++tj) Lj[tj] = sLj[wc + tj * 16 + cj];

        #pragma unroll
        for (int ti = 0; ti < 4; ++ti) {
            #pragma unroll
            for (int tj = 0; tj < 4; ++tj) {
                #pragma unroll
                for (int r = 0; r < 4; ++r) {
                    float u  = accv[ti][tj][r];
                    float nv = 0.2f - u;
                    bool same = (Li[ti * 4 + r] == Lj[tj]);
                    ull sm = __ballot(same);
                    if (sm == 0ull) {
                        // fast path (~88%): no same-label pair anywhere in the wave
                        ns += fmaxf(nv, 0.f);
                        ncw += (unsigned)__popcll(__ballot(nv > 0.f));
                    } else {
                        float pv = u - 0.01f;
                        bool n1 = !same && nv > 0.f;
                        bool p1 = same && pv > 0.f;   // diag self-excludes: dist(i,i)~0 < 0.01
                        ns += n1 ? nv : 0.f;
                        ps += p1 ? pv : 0.f;
                        ncw += (unsigned)__popcll(__ballot(n1));
                        pcw += (unsigned)__popcll(__ballot(p1));
                    }
                }
            }
        }
    }

    //================ Tail: block reduce + last-block finalize ================
    #pragma unroll
    for (int off = 32; off >= 1; off >>= 1) {
        ps += __shfl_down(ps, off);
        ns += __shfl_down(ns, off);
    }
    if (lane == 0) {
        redbuf[wave][0] = ps; redbuf[wave][1] = ns;
        redbuf[wave][2] = (float)pcw; redbuf[wave][3] = (float)ncw;
    }
    __syncthreads();
    if (tid == 0) {
        float a0 = 0, a1 = 0, a2 = 0, a3 = 0;
        #pragma unroll
        for (int w = 0; w < 4; ++w) {
            a0 += redbuf[w][0]; a1 += redbuf[w][1];
            a2 += redbuf[w][2]; a3 += redbuf[w][3];
        }
        atomicAdd(&accums[0], a0);
        atomicAdd(&accums[1], a1);
        atomicAdd(&accums[2], a2);
        atomicAdd(&accums[3], a3);
        __threadfence();
        unsigned old = atomicAdd(&ctrs[2], 1u);
        if (old == GRID - 1) {
            __threadfence();
            float A0 = __hip_atomic_load(&accums[0], __ATOMIC_RELAXED, __HIP_MEMORY_SCOPE_AGENT);
            float A1 = __hip_atomic_load(&accums[1], __ATOMIC_RELAXED, __HIP_MEMORY_SCOPE_AGENT);
            float A2 = __hip_atomic_load(&accums[2], __ATOMIC_RELAXED, __HIP_MEMORY_SCOPE_AGENT);
            float A3 = __hip_atomic_load(&accums[3], __ATOMIC_RELAXED, __HIP_MEMORY_SCOPE_AGENT);
            float A4 = __hip_atomic_load(&accums[4], __ATOMIC_RELAXED, __HIP_MEMORY_SCOPE_AGENT);
            float pos = A0 / (A2 + 1e-12f);
            float neg = A1 / (A3 + 1e-12f);
            out[0] = pos + neg + A4 * (0.1f / (float)NROWS);
        }
    }
}

extern "C" void kernel_launch(void* const* d_in, const int* in_sizes, int n_in,
                              void* d_out, int out_size, void* d_ws, size_t ws_size,
                              hipStream_t stream) {
    const float* embeds = (const float*)d_in[0];
    const int*   labels = (const int*)d_in[1];
    float* out = (float*)d_out;

    char* ws = (char*)d_ws;
    unsigned short* X = (unsigned short*)ws;                                  // 8192*320*2 = 5.24 MB
    unsigned short* Y = X + (size_t)NROWS * KAUG;                             // 5.24 MB
    unsigned int* ctrs = (unsigned int*)(ws + 2 * (size_t)NROWS * KAUG * 2);
    float* accums = (float*)((char*)ctrs + 16);                               // [ps, ns, pc, nc, reg]

    hipMemsetAsync(ctrs, 0, 64, stream);   // zero barrier/ticket/done counters + accums

    snr_fused_kernel<<<GRID, 256, 0, stream>>>(embeds, labels, X, Y, ctrs, accums, out);
}

// Round 7
// 273.712 us; speedup vs baseline: 1.3131x; 1.0584x over previous
//
#include <hip/hip_runtime.h>
#include <hip/hip_bf16.h>

#define NROWS 8192
#define DDIM  256
#define KAUG  320                  // 256 data + [a,2d,1] tail + zero pad to BK multiple
#define BT    128
#define BK    64
#define NIT   (KAUG / BK)          // 5
#define GT    (NROWS / BT)         // 64
#define NTILE (GT * GT)            // 4096
#define GRID  768                  // 3 blocks/CU co-resident (proven r4-r6; VGPR cap 168, LDS 33.9KB)

using bf16x8 = __attribute__((ext_vector_type(8))) __bf16;
using f32x4  = __attribute__((ext_vector_type(4))) float;
typedef unsigned long long ull;

__device__ __forceinline__ void glds16(const unsigned short* g, unsigned short* l) {
    // async global->LDS DMA, 16B/lane; LDS dest = wave-uniform base + lane*16
    __builtin_amdgcn_global_load_lds(
        (const __attribute__((address_space(1))) unsigned int*)g,
        (__attribute__((address_space(3))) unsigned int*)l, 16, 0, 0);
}

__device__ __forceinline__ unsigned short f2bf(float f) {
    unsigned int b = __float_as_uint(f);
    unsigned int r = b + 0x7fffu + ((b >> 16) & 1u);
    return (unsigned short)(r >> 16);
}

// Augmented-GEMM: dist(i,j) = X_i . Y_j with
//   X_i = [(-2a_i/256)*e_i, a_i, 2d_i, 1, 0...],  Y_j = [e_j, b_j, m_j, 1, 0...]
// MFMA accumulator IS dist. dist(i,i) = 0 (+-0.005) < 0.01 -> diagonal self-excludes.
__global__ __launch_bounds__(256, 3) void snr_fused_kernel(
    const float* __restrict__ x, const int* __restrict__ labels,
    unsigned short* __restrict__ X, unsigned short* __restrict__ Y,
    unsigned int* __restrict__ ctrs, float* __restrict__ accums,
    float* __restrict__ out)
{
    __shared__ __align__(16) unsigned short As[BT * BK];   // 16 KB, XOR-swizzled chunks
    __shared__ __align__(16) unsigned short Bs[BT * BK];   // 16 KB
    __shared__ __align__(16) int sLi[BT];
    __shared__ __align__(16) int sLj[BT];
    __shared__ float redbuf[4][4];

    const int tid  = threadIdx.x;
    const int lane = tid & 63;
    const int wave = tid >> 6;
    const int bid  = blockIdx.x;

    //================ Phase 1: rowstats -> build augmented X, Y ================
    float regw = 0.f;
    for (int row = bid * 4 + wave; row < NROWS; row += GRID * 4) {
        const float4 v = reinterpret_cast<const float4*>(x + (size_t)row * DDIM)[lane];
        float ss = v.x * v.x + v.y * v.y + v.z * v.z + v.w * v.w;
        float sm = v.x + v.y + v.z + v.w;
        #pragma unroll
        for (int off = 32; off >= 1; off >>= 1) {
            ss += __shfl_xor(ss, off);
            sm += __shfl_xor(sm, off);
        }
        float invn = 1.0f / sqrtf(ss);
        float Se = sm * invn;
        float m  = Se * (1.0f / DDIM);
        float s  = (ss * invn * invn) * (1.0f / DDIM);
        float b  = s - m * m;
        float a  = 1.0f / b;
        float d  = a * m;

        float cX = (-2.0f * a * (1.0f / 256.0f)) * invn;
        float cY = invn;
        ushort4 xo, yo;
        xo.x = f2bf(v.x * cX); xo.y = f2bf(v.y * cX);
        xo.z = f2bf(v.z * cX); xo.w = f2bf(v.w * cX);
        yo.x = f2bf(v.x * cY); yo.y = f2bf(v.y * cY);
        yo.z = f2bf(v.z * cY); yo.w = f2bf(v.w * cY);
        reinterpret_cast<ushort4*>(X + (size_t)row * KAUG)[lane] = xo;
        reinterpret_cast<ushort4*>(Y + (size_t)row * KAUG)[lane] = yo;
        if (lane < 16) {
            ushort4 tx = {0, 0, 0, 0}, ty = {0, 0, 0, 0};
            if (lane == 0) {
                tx.x = f2bf(a); tx.y = f2bf(2.0f * d); tx.z = f2bf(1.0f);
                ty.x = f2bf(b); ty.y = f2bf(m);        ty.z = f2bf(1.0f);
            }
            reinterpret_cast<ushort4*>(X + (size_t)row * KAUG + 256)[lane] = tx;
            reinterpret_cast<ushort4*>(Y + (size_t)row * KAUG + 256)[lane] = ty;
        }
        if (lane == 0) regw += fabsf(Se);
    }
    if (lane == 0) redbuf[wave][0] = regw;
    __syncthreads();
    if (tid == 0)
        atomicAdd(&accums[4], redbuf[0][0] + redbuf[1][0] + redbuf[2][0] + redbuf[3][0]);

    //================ Grid spin-barrier (all GRID blocks co-resident) ================
    __syncthreads();
    if (tid == 0) {
        __threadfence();
        atomicAdd(&ctrs[0], 1u);
        while (__hip_atomic_load(&ctrs[0], __ATOMIC_RELAXED, __HIP_MEMORY_SCOPE_AGENT) < GRID)
            __builtin_amdgcn_s_sleep(8);
    }
    __syncthreads();
    __threadfence();   // acquire: all blocks' X/Y visible

    //================ Phase 2: static slab of consecutive tiles (NO ticket atomic) ================
    const int wr = (wave >> 1) * 64;
    const int wc = (wave & 1) * 64;
    const int mrow = lane & 15;
    const int kch  = lane >> 4;       // 0..3
    const int subr = (lane >> 4) * 4;
    const int cj   = lane & 15;

    // staging: 4 chunks per array per thread: q=p*256+tid; row=q>>3; slot=q&7 holds kc=slot^(row&7)
    int ldRow[4], ldKc[4];
    #pragma unroll
    for (int p = 0; p < 4; ++p) {
        int q = p * 256 + tid;
        ldRow[p] = q >> 3;
        ldKc[p]  = (q & 7) ^ ((q >> 3) & 7);
    }

    // fragment LDS offsets (elems), swizzle-aware (r3-verified: zero conflicts)
    int offA[4][2], offB[4][2];
    #pragma unroll
    for (int t4 = 0; t4 < 4; ++t4) {
        int rA = wr + t4 * 16 + mrow;
        int rB = wc + t4 * 16 + mrow;
        #pragma unroll
        for (int h = 0; h < 2; ++h) {
            offA[t4][h] = (rA * 8 + ((h * 4 + kch) ^ (rA & 7))) * 8;
            offB[t4][h] = (rB * 8 + ((h * 4 + kch) ^ (rB & 7))) * 8;
        }
    }

    float ps = 0.f, ns = 0.f;
    unsigned int pcw = 0, ncw = 0;

    // 4096 = 256*6 + 512*5: blocks <256 take 6 consecutive tiles, rest take 5.
    // Consecutive tiles share the tile-row -> A-side L2 reuse.
    const int tstart = (bid < 256) ? bid * 6 : bid * 5 + 256;
    const int tcount = (bid < 256) ? 6 : 5;

    for (int k = 0; k < tcount; ++k) {
        const int t = tstart + k;
        const int rowBase = (t >> 6) * BT;
        const int colBase = (t & 63) * BT;

        __syncthreads();   // prior tile's epilogue (sLi/sLj reads) complete before overwrite

        // labels to LDS (the K-loop's first __syncthreads covers these writes)
        if (tid < BT) sLi[tid] = labels[rowBase + tid];
        else          sLj[tid - BT] = labels[colBase + tid - BT];

        f32x4 accv[4][4];
        #pragma unroll
        for (int a = 0; a < 4; ++a)
            #pragma unroll
            for (int b = 0; b < 4; ++b)
                accv[a][b] = (f32x4){0.f, 0.f, 0.f, 0.f};

        // K-loop: m97-style — __syncthreads() drains glds (vmcnt) before fragment reads
        #pragma unroll
        for (int it = 0; it < NIT; ++it) {
            const int ko = it * BK;
            #pragma unroll
            for (int p = 0; p < 4; ++p) {
                const unsigned short* gx = X + (size_t)(rowBase + ldRow[p]) * KAUG + ko + ldKc[p] * 8;
                const unsigned short* gy = Y + (size_t)(colBase + ldRow[p]) * KAUG + ko + ldKc[p] * 8;
                glds16(gx, &As[(p * 256 + tid) * 8]);
                glds16(gy, &Bs[(p * 256 + tid) * 8]);
            }
            __syncthreads();

            #pragma unroll
            for (int h = 0; h < 2; ++h) {
                bf16x8 aF[4], bF[4];
                #pragma unroll
                for (int t4 = 0; t4 < 4; ++t4) {
                    aF[t4] = *reinterpret_cast<const bf16x8*>(As + offA[t4][h]);
                    bF[t4] = *reinterpret_cast<const bf16x8*>(Bs + offB[t4][h]);
                }
                #pragma unroll
                for (int ti = 0; ti < 4; ++ti)
                    #pragma unroll
                    for (int tj = 0; tj < 4; ++tj)
                        accv[ti][tj] = __builtin_amdgcn_mfma_f32_16x16x32_bf16(
                            aF[ti], bF[tj], accv[ti][tj], 0, 0, 0);
            }
            __syncthreads();                // reads complete before next iter's DMA overwrite
        }

        // ---- epilogue: accv[ti][tj][r] == dist(i,j) ----
        int Li[16], Lj[4];
        #pragma unroll
        for (int t4 = 0; t4 < 4; ++t4) {
            int4 q4 = *reinterpret_cast<const int4*>(&sLi[wr + t4 * 16 + subr]);
            Li[t4 * 4 + 0] = q4.x; Li[t4 * 4 + 1] = q4.y;
            Li[t4 * 4 + 2] = q4.z; Li[t4 * 4 + 3] = q4.w;
        }
        #pragma unroll
        for (int tj = 0; tj < 4; ++tj) Lj[tj] = sLj[wc + tj * 16 + cj];

        #pragma unroll
        for (int ti = 0; ti < 4; ++ti) {
            #pragma unroll
            for (int tj = 0; tj < 4; ++tj) {
                #pragma unroll
                for (int r = 0; r < 4; ++r) {
                    float u  = accv[ti][tj][r];
                    float nv = 0.2f - u;
                    bool same = (Li[ti * 4 + r] == Lj[tj]);
                    ull sm = __ballot(same);
                    if (sm == 0ull) {
                        // fast path (~88%): no same-label pair anywhere in the wave
                        ns += fmaxf(nv, 0.f);
                        ncw += (unsigned)__popcll(__ballot(nv > 0.f));
                    } else {
                        float pv = u - 0.01f;
                        bool n1 = !same && nv > 0.f;
                        bool p1 = same && pv > 0.f;   // diag self-excludes: dist(i,i)~0 < 0.01
                        ns += n1 ? nv : 0.f;
                        ps += p1 ? pv : 0.f;
                        ncw += (unsigned)__popcll(__ballot(n1));
                        pcw += (unsigned)__popcll(__ballot(p1));
                    }
                }
            }
        }
    }

    //================ Tail: block reduce + last-block finalize ================
    #pragma unroll
    for (int off = 32; off >= 1; off >>= 1) {
        ps += __shfl_down(ps, off);
        ns += __shfl_down(ns, off);
    }
    if (lane == 0) {
        redbuf[wave][0] = ps; redbuf[wave][1] = ns;
        redbuf[wave][2] = (float)pcw; redbuf[wave][3] = (float)ncw;
    }
    __syncthreads();
    if (tid == 0) {
        float a0 = 0, a1 = 0, a2 = 0, a3 = 0;
        #pragma unroll
        for (int w = 0; w < 4; ++w) {
            a0 += redbuf[w][0]; a1 += redbuf[w][1];
            a2 += redbuf[w][2]; a3 += redbuf[w][3];
        }
        atomicAdd(&accums[0], a0);
        atomicAdd(&accums[1], a1);
        atomicAdd(&accums[2], a2);
        atomicAdd(&accums[3], a3);
        __threadfence();
        unsigned old = atomicAdd(&ctrs[2], 1u);
        if (old == GRID - 1) {
            __threadfence();
            float A0 = __hip_atomic_load(&accums[0], __ATOMIC_RELAXED, __HIP_MEMORY_SCOPE_AGENT);
            float A1 = __hip_atomic_load(&accums[1], __ATOMIC_RELAXED, __HIP_MEMORY_SCOPE_AGENT);
            float A2 = __hip_atomic_load(&accums[2], __ATOMIC_RELAXED, __HIP_MEMORY_SCOPE_AGENT);
            float A3 = __hip_atomic_load(&accums[3], __ATOMIC_RELAXED, __HIP_MEMORY_SCOPE_AGENT);
            float A4 = __hip_atomic_load(&accums[4], __ATOMIC_RELAXED, __HIP_MEMORY_SCOPE_AGENT);
            float pos = A0 / (A2 + 1e-12f);
            float neg = A1 / (A3 + 1e-12f);
            out[0] = pos + neg + A4 * (0.1f / (float)NROWS);
        }
    }
}

extern "C" void kernel_launch(void* const* d_in, const int* in_sizes, int n_in,
                              void* d_out, int out_size, void* d_ws, size_t ws_size,
                              hipStream_t stream) {
    const float* embeds = (const float*)d_in[0];
    const int*   labels = (const int*)d_in[1];
    float* out = (float*)d_out;

    char* ws = (char*)d_ws;
    unsigned short* X = (unsigned short*)ws;                                  // 8192*320*2 = 5.24 MB
    unsigned short* Y = X + (size_t)NROWS * KAUG;                             // 5.24 MB
    unsigned int* ctrs = (unsigned int*)(ws + 2 * (size_t)NROWS * KAUG * 2);
    float* accums = (float*)((char*)ctrs + 16);                               // [ps, ns, pc, nc, reg]

    hipMemsetAsync(ctrs, 0, 64, stream);   // zero barrier/done counters + accums

    snr_fused_kernel<<<GRID, 256, 0, stream>>>(embeds, labels, X, Y, ctrs, accums, out);
}

// Round 8
// 258.363 us; speedup vs baseline: 1.3911x; 1.0594x over previous
//
#include <hip/hip_runtime.h>
#include <hip/hip_bf16.h>

#define NROWS 8192
#define DDIM  256
#define BT    128
#define BK    64
#define NIT   (DDIM / BK)          // 4
#define GT    (NROWS / BT)         // 64
#define NBT   (GT * (GT + 1) / 2)  // 2080 triangular tiles
#define GRID  768                  // 3 blocks/CU co-resident (proven r4-r7)

using bf16x8 = __attribute__((ext_vector_type(8))) __bf16;
using f32x4  = __attribute__((ext_vector_type(4))) float;
typedef unsigned long long ull;

__device__ __forceinline__ void glds16(const unsigned short* g, unsigned short* l) {
    // async global->LDS DMA, 16B/lane; LDS dest = wave-uniform base + lane*16
    __builtin_amdgcn_global_load_lds(
        (const __attribute__((address_space(1))) unsigned int*)g,
        (__attribute__((address_space(3))) unsigned int*)l, 16, 0, 0);
}

__device__ __forceinline__ unsigned short f2bf(float f) {
    unsigned int b = __float_as_uint(f);
    unsigned int r = b + 0x7fffu + ((b >> 16) & 1u);
    return (unsigned short)(r >> 16);
}

// Gram formulation (r2-verified): e = row-normalized embeds (bf16, 4 MB — L2-resident/XCD).
// u = raw MFMA acc = e_i.e_j * 256;  g2 = u/128 = 2*mean(e_i e_j).
// dist(i,j) = 1 + a_i*(b_j - g2) + d_i*m2_j   with a=1/b, d=a*m, b=s-m^2, m2=2m.
// Triangle: one u serves dist(i,j) AND dist(j,i).
__global__ __launch_bounds__(256, 3) void snr_fused_kernel(
    const float* __restrict__ x, const int* __restrict__ labels,
    unsigned short* __restrict__ ebf, float4* __restrict__ gstats,
    unsigned int* __restrict__ ctrs, float* __restrict__ accums,
    float* __restrict__ out)
{
    __shared__ __align__(16) unsigned short As[BT * BK];   // 16 KB, XOR-swizzled chunks
    __shared__ __align__(16) unsigned short Bs[BT * BK];   // 16 KB
    __shared__ __align__(16) float4 sI4[BT];               // {a,d,b,m2} per I-row
    __shared__ __align__(16) float4 sJ4[BT];               // per J-col
    __shared__ __align__(16) int sLi[BT];
    __shared__ __align__(16) int sLj[BT];
    __shared__ float redbuf[4][4];

    const int tid  = threadIdx.x;
    const int lane = tid & 63;
    const int wave = tid >> 6;
    const int bid  = blockIdx.x;

    //================ Phase 1: rowstats -> ebf + gstats ================
    float regw = 0.f;
    for (int row = bid * 4 + wave; row < NROWS; row += GRID * 4) {
        const float4 v = reinterpret_cast<const float4*>(x + (size_t)row * DDIM)[lane];
        float ss = v.x * v.x + v.y * v.y + v.z * v.z + v.w * v.w;
        float sm = v.x + v.y + v.z + v.w;
        #pragma unroll
        for (int off = 32; off >= 1; off >>= 1) {
            ss += __shfl_xor(ss, off);
            sm += __shfl_xor(sm, off);
        }
        float invn = 1.0f / sqrtf(ss);
        ushort4 o;
        o.x = f2bf(v.x * invn); o.y = f2bf(v.y * invn);
        o.z = f2bf(v.z * invn); o.w = f2bf(v.w * invn);
        reinterpret_cast<ushort4*>(ebf + (size_t)row * DDIM)[lane] = o;
        if (lane == 0) {
            float Se  = sm * invn;
            float m = Se * (1.0f / DDIM);
            float s = (ss * invn * invn) * (1.0f / DDIM);
            float b = s - m * m;
            float a = 1.0f / b;
            gstats[row] = make_float4(a, a * m, b, 2.0f * m);
            regw += fabsf(Se);
        }
    }
    if (lane == 0) redbuf[wave][0] = regw;
    __syncthreads();
    if (tid == 0)
        atomicAdd(&accums[4], redbuf[0][0] + redbuf[1][0] + redbuf[2][0] + redbuf[3][0]);

    //================ Grid spin-barrier (all GRID blocks co-resident) ================
    __syncthreads();
    if (tid == 0) {
        __threadfence();
        atomicAdd(&ctrs[0], 1u);
        while (__hip_atomic_load(&ctrs[0], __ATOMIC_RELAXED, __HIP_MEMORY_SCOPE_AGENT) < GRID)
            __builtin_amdgcn_s_sleep(8);
    }
    __syncthreads();
    __threadfence();   // acquire: all blocks' ebf/gstats visible

    //================ Phase 2: static slab of consecutive triangular tiles ================
    const int wr = (wave >> 1) * 64;
    const int wc = (wave & 1) * 64;
    const int mrow = lane & 15;
    const int kch  = lane >> 4;
    const int subr = (lane >> 4) * 4;
    const int cj   = lane & 15;

    // staging: q=p*256+tid; row=q>>3; slot=q&7 holds kc=slot^(row&7)
    int ldRow[4], ldKc[4];
    #pragma unroll
    for (int p = 0; p < 4; ++p) {
        int q = p * 256 + tid;
        ldRow[p] = q >> 3;
        ldKc[p]  = (q & 7) ^ ((q >> 3) & 7);
    }

    // fragment LDS offsets (elems), swizzle-aware (r3/r7-verified: zero conflicts)
    int offA[4][2], offB[4][2];
    #pragma unroll
    for (int t4 = 0; t4 < 4; ++t4) {
        int rA = wr + t4 * 16 + mrow;
        int rB = wc + t4 * 16 + mrow;
        #pragma unroll
        for (int h = 0; h < 2; ++h) {
            offA[t4][h] = (rA * 8 + ((h * 4 + kch) ^ (rA & 7))) * 8;
            offB[t4][h] = (rB * 8 + ((h * 4 + kch) ^ (rB & 7))) * 8;
        }
    }

    float ps = 0.f, ns = 0.f;
    unsigned int pcw = 0, ncw = 0;

    // 2080 = 544*3 + 224*2 consecutive-tile slabs
    const int tstart = (bid < 544) ? bid * 3 : 1632 + (bid - 544) * 2;
    const int tcount = (bid < 544) ? 3 : 2;

    // decode triangular tstart -> (bi,bj), bi<=bj  (r3-proven decode)
    int bi = (int)((2.0f * GT + 1.0f
                    - sqrtf((2.0f * GT + 1.0f) * (2.0f * GT + 1.0f) - 8.0f * (float)tstart)) * 0.5f);
    while ((bi + 1) * GT - ((bi + 1) * bi) / 2 <= tstart) ++bi;
    while (bi * GT - (bi * (bi - 1)) / 2 > tstart) --bi;
    int bj = bi + (tstart - (bi * GT - (bi * (bi - 1)) / 2));

    for (int k = 0; k < tcount; ++k) {
        const int rowBase = bi * BT;
        const int colBase = bj * BT;
        const bool diag = (bi == bj);
        // advance for next iteration
        if (++bj == GT) { ++bi; bj = bi; }

        __syncthreads();   // prior tile's epilogue LDS reads complete before overwrite

        // stage stats + labels (covered by K-loop's first __syncthreads)
        if (tid < BT) {
            sI4[tid] = gstats[rowBase + tid];
            sLi[tid] = labels[rowBase + tid];
        } else {
            int tt = tid - BT;
            sJ4[tt] = gstats[colBase + tt];
            sLj[tt] = labels[colBase + tt];
        }

        f32x4 accv[4][4];
        #pragma unroll
        for (int a = 0; a < 4; ++a)
            #pragma unroll
            for (int b = 0; b < 4; ++b)
                accv[a][b] = (f32x4){0.f, 0.f, 0.f, 0.f};

        // K-loop: m97-style — __syncthreads() drains glds before fragment reads
        #pragma unroll
        for (int it = 0; it < NIT; ++it) {
            const int ko = it * BK;
            #pragma unroll
            for (int p = 0; p < 4; ++p) {
                const unsigned short* gx = ebf + (size_t)(rowBase + ldRow[p]) * DDIM + ko + ldKc[p] * 8;
                const unsigned short* gy = ebf + (size_t)(colBase + ldRow[p]) * DDIM + ko + ldKc[p] * 8;
                glds16(gx, &As[(p * 256 + tid) * 8]);
                glds16(gy, &Bs[(p * 256 + tid) * 8]);
            }
            __syncthreads();

            #pragma unroll
            for (int h = 0; h < 2; ++h) {
                bf16x8 aF[4], bF[4];
                #pragma unroll
                for (int t4 = 0; t4 < 4; ++t4) {
                    aF[t4] = *reinterpret_cast<const bf16x8*>(As + offA[t4][h]);
                    bF[t4] = *reinterpret_cast<const bf16x8*>(Bs + offB[t4][h]);
                }
                #pragma unroll
                for (int ti = 0; ti < 4; ++ti)
                    #pragma unroll
                    for (int tj = 0; tj < 4; ++tj)
                        accv[ti][tj] = __builtin_amdgcn_mfma_f32_16x16x32_bf16(
                            aF[ti], bF[tj], accv[ti][tj], 0, 0, 0);
            }
            __syncthreads();                // reads complete before next iter's DMA overwrite
        }

        // ---- epilogue: u = accv = 256*g; dual-side distmat ----
        float aJ[4], dJ[4], bJ[4], mJ[4];
        int Lj4[4];
        #pragma unroll
        for (int tj = 0; tj < 4; ++tj) {
            int lj = wc + tj * 16 + cj;
            float4 e = sJ4[lj];
            aJ[tj] = e.x; dJ[tj] = e.y; bJ[tj] = e.z; mJ[tj] = e.w;
            Lj4[tj] = sLj[lj];
        }

        if (!diag) {
            #pragma unroll
            for (int ti = 0; ti < 4; ++ti) {
                #pragma unroll
                for (int r = 0; r < 4; ++r) {
                    int li = wr + ti * 16 + subr + r;
                    float4 f = sI4[li];
                    float aR = f.x, dR = f.y, bR = f.z, mR = f.w;
                    int LR = sLi[li];
                    #pragma unroll
                    for (int tj = 0; tj < 4; ++tj) {
                        float g2 = accv[ti][tj][r] * (1.0f / 128.0f);
                        float dij = fmaf(aR, bJ[tj] - g2, fmaf(dR, mJ[tj], 1.0f));
                        float dji = fmaf(aJ[tj], bR - g2, fmaf(dJ[tj], mR, 1.0f));
                        bool same = (LR == Lj4[tj]);
                        ull ms = __ballot(same);
                        float nv1 = 0.2f - dij, nv2 = 0.2f - dji;
                        if (ms == 0ull) {
                            // fast path (~88%): no same-label pair anywhere in the wave
                            ns += fmaxf(nv1, 0.f) + fmaxf(nv2, 0.f);
                            ncw += (unsigned)__popcll(__ballot(nv1 > 0.f))
                                 + (unsigned)__popcll(__ballot(nv2 > 0.f));
                        } else {
                            float pv1 = dij - 0.01f, pv2 = dji - 0.01f;
                            bool n1 = !same && nv1 > 0.f, n2 = !same && nv2 > 0.f;
                            bool p1 = same && pv1 > 0.f,  p2 = same && pv2 > 0.f;
                            ns += (n1 ? nv1 : 0.f) + (n2 ? nv2 : 0.f);
                            ps += (p1 ? pv1 : 0.f) + (p2 ? pv2 : 0.f);
                            ncw += (unsigned)__popcll(__ballot(n1)) + (unsigned)__popcll(__ballot(n2));
                            pcw += (unsigned)__popcll(__ballot(p1)) + (unsigned)__popcll(__ballot(p2));
                        }
                    }
                }
            }
        } else {
            #pragma unroll
            for (int ti = 0; ti < 4; ++ti) {
                #pragma unroll
                for (int r = 0; r < 4; ++r) {
                    int li = wr + ti * 16 + subr + r;
                    float4 f = sI4[li];
                    float aR = f.x, dR = f.y;
                    int LR = sLi[li];
                    #pragma unroll
                    for (int tj = 0; tj < 4; ++tj) {
                        int lj = wc + tj * 16 + cj;
                        float g2 = accv[ti][tj][r] * (1.0f / 128.0f);
                        float dij = fmaf(aR, bJ[tj] - g2, fmaf(dR, mJ[tj], 1.0f));
                        bool same = (LR == Lj4[tj]);
                        float nv1 = 0.2f - dij;
                        float pv1 = dij - 0.01f;
                        bool n1 = !same && nv1 > 0.f;
                        bool p1 = same && (li != lj) && pv1 > 0.f;
                        ns += n1 ? nv1 : 0.f;
                        ps += p1 ? pv1 : 0.f;
                        ncw += (unsigned)__popcll(__ballot(n1));
                        pcw += (unsigned)__popcll(__ballot(p1));
                    }
                }
            }
        }
    }

    //================ Tail: block reduce + last-block finalize ================
    #pragma unroll
    for (int off = 32; off >= 1; off >>= 1) {
        ps += __shfl_down(ps, off);
        ns += __shfl_down(ns, off);
    }
    if (lane == 0) {
        redbuf[wave][0] = ps; redbuf[wave][1] = ns;
        redbuf[wave][2] = (float)pcw; redbuf[wave][3] = (float)ncw;
    }
    __syncthreads();
    if (tid == 0) {
        float a0 = 0, a1 = 0, a2 = 0, a3 = 0;
        #pragma unroll
        for (int w = 0; w < 4; ++w) {
            a0 += redbuf[w][0]; a1 += redbuf[w][1];
            a2 += redbuf[w][2]; a3 += redbuf[w][3];
        }
        atomicAdd(&accums[0], a0);
        atomicAdd(&accums[1], a1);
        atomicAdd(&accums[2], a2);
        atomicAdd(&accums[3], a3);
        __threadfence();
        unsigned old = atomicAdd(&ctrs[2], 1u);
        if (old == GRID - 1) {
            __threadfence();
            float A0 = __hip_atomic_load(&accums[0], __ATOMIC_RELAXED, __HIP_MEMORY_SCOPE_AGENT);
            float A1 = __hip_atomic_load(&accums[1], __ATOMIC_RELAXED, __HIP_MEMORY_SCOPE_AGENT);
            float A2 = __hip_atomic_load(&accums[2], __ATOMIC_RELAXED, __HIP_MEMORY_SCOPE_AGENT);
            float A3 = __hip_atomic_load(&accums[3], __ATOMIC_RELAXED, __HIP_MEMORY_SCOPE_AGENT);
            float A4 = __hip_atomic_load(&accums[4], __ATOMIC_RELAXED, __HIP_MEMORY_SCOPE_AGENT);
            float pos = A0 / (A2 + 1e-12f);
            float neg = A1 / (A3 + 1e-12f);
            out[0] = pos + neg + A4 * (0.1f / (float)NROWS);
        }
    }
}

extern "C" void kernel_launch(void* const* d_in, const int* in_sizes, int n_in,
                              void* d_out, int out_size, void* d_ws, size_t ws_size,
                              hipStream_t stream) {
    const float* embeds = (const float*)d_in[0];
    const int*   labels = (const int*)d_in[1];
    float* out = (float*)d_out;

    char* ws = (char*)d_ws;
    unsigned short* ebf = (unsigned short*)ws;                        // 8192*256*2 = 4 MB (L2-resident/XCD)
    float4* gstats = (float4*)(ws + (size_t)NROWS * DDIM * 2);        // 128 KB
    unsigned int* ctrs = (unsigned int*)((char*)gstats + NROWS * sizeof(float4));
    float* accums = (float*)((char*)ctrs + 16);                       // [ps, ns, pc, nc, reg]

    hipMemsetAsync(ctrs, 0, 64, stream);   // zero barrier/done counters + accums

    snr_fused_kernel<<<GRID, 256, 0, stream>>>(embeds, labels, ebf, gstats, ctrs, accums, out);
}